// Round 1
// baseline (261.487 us; speedup 1.0000x reference)
//
#include <hip/hip_runtime.h>
#include <math.h>

// AttentionDecoder R8: 3 kernels, ZERO global atomics.
// prep (wave-parallel MLP) | score (PURE GEMV, unchanged) | finish (single
// block 1024 thr: LDS hist + scan + gather-to-LDS + exact select + categorical).
// R7 lesson: same-address global atomics ~50ns serialized; the 196-block
// hist/gather pair carried 4+ such chains (Z, done x2, pos) + 2 launches.
// Post-score data is only 0.8MB (L2-resident) -> one CU does it all in LDS.

#define CAP 4096
#define NEG_INF (-__builtin_inff())
#define HC 4          // LDS histogram replicas (cuts hot-bin atomic serialization)
#define HSTRIDE 2052  // 2048+4: replicas land on distinct banks (2052%32=4)

// order-preserving float->uint mapping (monotone increasing)
__device__ __forceinline__ unsigned int f2ord(float f){
  unsigned int b = __float_as_uint(f);
  return (b & 0x80000000u) ? ~b : (b | 0x80000000u);
}
__device__ __forceinline__ unsigned int rotl32(unsigned int x, int d){
  return (x << d) | (x >> (32 - d));
}

// JAX partitionable threefry, key (0,42): x0=idx>>32(=0), x1=idx; bits=w0^w1.
// gumbel = -log(-log(u)), u = bitcast((bits>>9)|0x3f800000)-1 clamped to tiny.
__device__ float gumbel_from_idx(unsigned int idx){
  unsigned int x0 = 0u, x1 = idx;
  const unsigned int ks0 = 0u, ks1 = 42u;
  const unsigned int ks2 = 0u ^ 42u ^ 0x1BD11BDAu;
  x0 += ks0; x1 += ks1;
#define TF_RND(r) { x0 += x1; x1 = rotl32(x1, (r)); x1 ^= x0; }
  TF_RND(13) TF_RND(15) TF_RND(26) TF_RND(6)
  x0 += ks1; x1 += ks2 + 1u;
  TF_RND(17) TF_RND(29) TF_RND(16) TF_RND(24)
  x0 += ks2; x1 += ks0 + 2u;
  TF_RND(13) TF_RND(15) TF_RND(26) TF_RND(6)
  x0 += ks0; x1 += ks1 + 3u;
  TF_RND(17) TF_RND(29) TF_RND(16) TF_RND(24)
  x0 += ks1; x1 += ks2 + 4u;
  TF_RND(13) TF_RND(15) TF_RND(26) TF_RND(6)
  x0 += ks2; x1 += ks0 + 5u;
#undef TF_RND
  unsigned int bits = x0 ^ x1;
  unsigned int fb = (bits >> 9) | 0x3f800000u;
  float f = __uint_as_float(fb) - 1.0f;
  float u = (f < 1.17549435e-38f) ? 1.17549435e-38f : f;
  return -logf(-logf(u));
}

// Wave-parallel MLP: q = Wq @ [cur;ctx] (half-wave per row, coalesced float4,
// 5-shfl reduce), then v = Wk^T q (split-K across 2 thread-halves).
__global__ __launch_bounds__(256) void k_prep(const float* __restrict__ cur,
    const float* __restrict__ ctx, const float* __restrict__ Wq,
    const float* __restrict__ Wk, float* __restrict__ v){
  __shared__ float q[128];
  __shared__ float vpart[256];
  int t = threadIdx.x;
  int lane = t & 63, wave = t >> 6;
  int hl = lane & 31, hi = lane >> 5;
  // lane's comb chunks: j=4*hl (cur) and j=128+4*hl (ctx)
  float4 cb0 = ((const float4*)cur)[hl];
  float4 cb1 = ((const float4*)ctx)[hl];
  const float4* Wq4 = (const float4*)Wq;
  #pragma unroll 4
  for (int i = 0; i < 16; ++i){
    int row = wave * 32 + 2 * i + hi;          // 4 waves x 16 iters x 2 rows = 128
    float4 w0 = Wq4[row * 64 + hl];            // coalesced 512B per half-wave
    float4 w1 = Wq4[row * 64 + 32 + hl];
    float d = fmaf(w0.x, cb0.x, fmaf(w0.y, cb0.y, fmaf(w0.z, cb0.z, w0.w * cb0.w)));
    d = fmaf(w1.x, cb1.x, fmaf(w1.y, cb1.y, fmaf(w1.z, cb1.z, fmaf(w1.w, cb1.w, d))));
    d += __shfl_xor(d, 1, 64);
    d += __shfl_xor(d, 2, 64);
    d += __shfl_xor(d, 4, 64);
    d += __shfl_xor(d, 8, 64);
    d += __shfl_xor(d, 16, 64);
    if (hl == 0) q[row] = d;
  }
  __syncthreads();
  // v[col] = sum_h q[h]*Wk[h*128+col]; split h-range across two 128-thread halves
  int col = t & 127, half = t >> 7;
  const float* wkp = Wk + half * 64 * 128 + col;
  const float* qp  = q + half * 64;
  float acc = 0.f;
  #pragma unroll 8
  for (int h = 0; h < 64; ++h) acc = fmaf(qp[h], wkp[h * 128], acc);
  vpart[t] = acc;
  __syncthreads();
  if (t < 128) v[t] = vpart[t] + vpart[t + 128];
}

// PURE GEMV (unchanged, proven). Half-wave per row (32 lanes x float4 = 512B),
// 16 rows/wave, 64 rows/block. All 8 loads issued before any FMA. No atomics.
__global__ __launch_bounds__(256) void k_score(const float* __restrict__ cand,
    const int* __restrict__ mask, const float* __restrict__ v,
    float* __restrict__ scores, float* __restrict__ out, int N){
  const float NLOG = logf(1e-10f);
  int t = threadIdx.x;
  int lane = t & 63, wave = t >> 6;
  int hi = lane >> 5, hl = lane & 31;
  float4 v4 = ((const float4*)v)[hl];
  const float4* cp = (const float4*)cand;
  int base = (blockIdx.x * 4 + wave) * 16;
  float4 c[8];
  #pragma unroll
  for (int k = 0; k < 8; ++k){                 // phase 1: 8 loads in flight
    int r = base + 2 * k + hi;
    r = (r < N) ? r : (N - 1);                 // clamp: load stays unconditional
    c[k] = cp[(size_t)r * 32 + hl];
  }
  float p[8];
  #pragma unroll
  for (int k = 0; k < 8; ++k)                  // phase 2: consume
    p[k] = fmaf(c[k].x, v4.x, fmaf(c[k].y, v4.y, fmaf(c[k].z, v4.z, c[k].w * v4.w)));
  #pragma unroll
  for (int k = 0; k < 8; ++k){                 // 8 independent 5-shfl chains
    p[k] += __shfl_xor(p[k], 1, 64);
    p[k] += __shfl_xor(p[k], 2, 64);
    p[k] += __shfl_xor(p[k], 4, 64);
    p[k] += __shfl_xor(p[k], 8, 64);
    p[k] += __shfl_xor(p[k], 16, 64);
  }
  float sv = p[0];
  #pragma unroll
  for (int k = 1; k < 8; ++k) sv = (hl == k) ? p[k] : sv;
  if (hl < 8){                                 // writer lanes
    int r = base + 2 * hl + hi;
    if (r < N) scores[r] = mask[r] ? sv : NEG_INF;
  }
  if (t < 16){                                 // default output value, float4
    int o4 = blockIdx.x * 16 + t;
    if (o4 * 4 + 3 < N){
      ((float4*)out)[o4] = make_float4(NLOG, NLOG, NLOG, NLOG);
    } else {
      #pragma unroll
      for (int e = 0; e < 4; ++e){ int i = o4 * 4 + e; if (i < N) out[i] = NLOG; }
    }
  }
}

// Single block, 1024 threads. scores (0.8MB) is L2/L3-hot after k_score.
// LDS-replicated histogram + Z | suffix scan -> bin edge | gather into LDS |
// exact rank-select | renorm + scatter-rewrite | threefry-gumbel categorical.
// No global atomics, no done-counters, no threadfence, no global hist/buf.
__global__ __launch_bounds__(1024) void k_finish(const float* __restrict__ scores,
    float* __restrict__ out, int N, int ktop){
  __shared__ unsigned int lh[HC * HSTRIDE];    // phase A hist; aliased in phase C
  __shared__ unsigned int htot[2048];
  __shared__ unsigned int suf[256];
  __shared__ float wred[16];
  __shared__ float rv[16], rl[16];
  __shared__ unsigned int ri[16];
  __shared__ float zsh, thr_sh, lnD_sh;
  __shared__ unsigned int u_lo_sh;
  __shared__ int csel_sh, pos_sh, C_sh;
  float* s_lds = (float*)lh;                   // [0 .. CAP)   phase C only
  unsigned int* i_lds = lh + CAP;              // [CAP .. 2*CAP) phase C only

  int t = threadIdx.x;
  int lane = t & 63, wave = t >> 6;
  unsigned int mycopy = (unsigned int)(t & (HC - 1)) * HSTRIDE;

  for (int k = t; k < HC * HSTRIDE; k += 1024) lh[k] = 0u;
  if (t == 0) pos_sh = 0;
  __syncthreads();

  // ---- phase A: histogram + Z (4 float4 loads in flight per thread) ----
  float ez = 0.f;
  const float4* sp4 = (const float4*)scores;
  int nf = N >> 2;
  const float4 SENT = make_float4(NEG_INF, NEG_INF, NEG_INF, NEG_INF);
#define HVISIT(s_) { float sx = (s_); if (sx > NEG_INF){ \
    atomicAdd(&lh[mycopy + (f2ord(sx) >> 21)], 1u); ez += expf(sx); } }
  for (int f = t; f < nf; f += 4096){
    float4 c0 = sp4[f];
    float4 c1 = (f + 1024 < nf) ? sp4[f + 1024] : SENT;
    float4 c2 = (f + 2048 < nf) ? sp4[f + 2048] : SENT;
    float4 c3 = (f + 3072 < nf) ? sp4[f + 3072] : SENT;
    HVISIT(c0.x) HVISIT(c0.y) HVISIT(c0.z) HVISIT(c0.w)
    HVISIT(c1.x) HVISIT(c1.y) HVISIT(c1.z) HVISIT(c1.w)
    HVISIT(c2.x) HVISIT(c2.y) HVISIT(c2.z) HVISIT(c2.w)
    HVISIT(c3.x) HVISIT(c3.y) HVISIT(c3.z) HVISIT(c3.w)
  }
  for (int i = (nf << 2) + t; i < N; i += 1024) HVISIT(scores[i])
#undef HVISIT
  #pragma unroll
  for (int off = 32; off; off >>= 1) ez += __shfl_xor(ez, off, 64);
  if (lane == 0) wred[wave] = ez;
  __syncthreads();
  if (t == 0){
    float z = 0.f;
    for (int w = 0; w < 16; ++w) z += wred[w];
    zsh = z; csel_sh = -1;
  }
  for (int k = t; k < 2048; k += 1024){        // merge hist replicas
    unsigned int c = 0;
    #pragma unroll
    for (int cc = 0; cc < HC; ++cc) c += lh[cc * HSTRIDE + k];
    htot[k] = c;
  }
  __syncthreads();

  // ---- suffix scan over 256 superbins -> bin lower edge of ktop-th score ----
  if (t < 256){
    unsigned int csum = 0;
    #pragma unroll
    for (int k = 0; k < 8; ++k) csum += htot[t * 8 + k];
    suf[t] = csum;
  }
  __syncthreads();
  for (int d = 1; d < 256; d <<= 1){
    unsigned int add = 0u;
    if (t < 256 && t + d < 256) add = suf[t + d];
    __syncthreads();
    if (t < 256) suf[t] += add;
    __syncthreads();
  }
  if (t < 256){
    unsigned int st = suf[t];
    unsigned int sn = (t < 255) ? suf[t + 1] : 0u;
    if (st >= (unsigned)ktop && sn < (unsigned)ktop) csel_sh = t;   // unique
  }
  __syncthreads();
  if (t == 0){
    int b_sel = 0;
    if (csel_sh >= 0){
      int c = csel_sh;
      unsigned int cum = (c < 255) ? suf[c + 1] : 0u;
      for (int b = 8 * c + 7; b >= 8 * c; --b){
        cum += htot[b];
        if (cum >= (unsigned)ktop){ b_sel = b; break; }
      }
    }
    u_lo_sh = ((unsigned int)b_sel) << 21;
  }
  __syncthreads();

  // ---- phase C: gather superset of top-ktop straight into LDS (L2-hot) ----
  unsigned int u_lo = u_lo_sh;
#define GVISIT(s_, i_) { float sx = (s_); if (sx > NEG_INF && f2ord(sx) >= u_lo){ \
    int p = atomicAdd(&pos_sh, 1); \
    if (p < CAP){ s_lds[p] = sx; i_lds[p] = (unsigned int)(i_); } } }
  for (int f = t; f < nf; f += 4096){
    float4 c0 = sp4[f];
    float4 c1 = (f + 1024 < nf) ? sp4[f + 1024] : SENT;
    float4 c2 = (f + 2048 < nf) ? sp4[f + 2048] : SENT;
    float4 c3 = (f + 3072 < nf) ? sp4[f + 3072] : SENT;
    GVISIT(c0.x, 4*f)          GVISIT(c0.y, 4*f+1)
    GVISIT(c0.z, 4*f+2)        GVISIT(c0.w, 4*f+3)
    GVISIT(c1.x, 4*(f+1024))   GVISIT(c1.y, 4*(f+1024)+1)
    GVISIT(c1.z, 4*(f+1024)+2) GVISIT(c1.w, 4*(f+1024)+3)
    GVISIT(c2.x, 4*(f+2048))   GVISIT(c2.y, 4*(f+2048)+1)
    GVISIT(c2.z, 4*(f+2048)+2) GVISIT(c2.w, 4*(f+2048)+3)
    GVISIT(c3.x, 4*(f+3072))   GVISIT(c3.y, 4*(f+3072)+1)
    GVISIT(c3.z, 4*(f+3072)+2) GVISIT(c3.w, 4*(f+3072)+3)
  }
  for (int i = (nf << 2) + t; i < N; i += 1024) GVISIT(scores[i], i)
#undef GVISIT
  __syncthreads();
  if (t == 0){ C_sh = (pos_sh > CAP) ? CAP : pos_sh; thr_sh = NEG_INF; }
  __syncthreads();
  int C = C_sh;

  // ---- exact rank-select on C entries (broadcast LDS reads) ----
  if (C > ktop){
    for (int j = t; j < C; j += 1024){
      float sj = s_lds[j];
      int g = 0, e = 0;
      for (int k2 = 0; k2 < C; ++k2){
        float sk = s_lds[k2];
        g += (sk > sj);
        e += (sk == sj);
      }
      if (g < ktop && g + e >= ktop) thr_sh = sj;   // all writers same value
    }
  }
  __syncthreads();
  float s_thr = thr_sh;
  float part = 0.f;
  for (int j = t; j < C; j += 1024){
    float sj = s_lds[j];
    if (sj >= s_thr) part += expf(sj);
  }
  #pragma unroll
  for (int off = 32; off; off >>= 1) part += __shfl_xor(part, off, 64);
  if (lane == 0) wred[wave] = part;
  __syncthreads();
  if (t == 0){
    float T = 0.f;
    for (int w = 0; w < 16; ++w) T += wred[w];
    lnD_sh = logf(T + 1e-10f * zsh);     // D = Z*(sum_top p + 1e-10)
  }
  __syncthreads();
  float lnD = lnD_sh;
  // rewrite included entries (everything else already NLOG from k_score)
  for (int j = t; j < C; j += 1024){
    float sj = s_lds[j];
    if (sj >= s_thr) out[i_lds[j]] = logf(expf(sj - lnD) + 1e-10f);
  }
  // gumbel categorical over included entries, tie-break lower idx
  float bestv = NEG_INF, bestlogit = NEG_INF;
  unsigned int bestidx = 0xFFFFFFFFu;
  for (int j = t; j < C; j += 1024){
    float sj = s_lds[j];
    if (sj >= s_thr){
      unsigned int idx = i_lds[j];
      float logit = sj - lnD;            // log(filtered)
      float val = logit + gumbel_from_idx(idx);
      if (val > bestv || (val == bestv && idx < bestidx)){
        bestv = val; bestlogit = logit; bestidx = idx;
      }
    }
  }
  #pragma unroll
  for (int off = 32; off; off >>= 1){
    float ov = __shfl_xor(bestv, off, 64);
    float ol = __shfl_xor(bestlogit, off, 64);
    unsigned int oi = (unsigned int)__shfl_xor((int)bestidx, off, 64);
    if (ov > bestv || (ov == bestv && oi < bestidx)){
      bestv = ov; bestlogit = ol; bestidx = oi;
    }
  }
  if (lane == 0){ rv[wave] = bestv; rl[wave] = bestlogit; ri[wave] = bestidx; }
  __syncthreads();
  if (t == 0){
    for (int w = 1; w < 16; ++w){
      if (rv[w] > rv[0] || (rv[w] == rv[0] && ri[w] < ri[0])){
        rv[0] = rv[w]; rl[0] = rl[w]; ri[0] = ri[w];
      }
    }
    out[N] = rl[0];                 // log_prob_action
    out[N + 1] = (float)ri[0];      // action_idx
  }
}

extern "C" void kernel_launch(void* const* d_in, const int* in_sizes, int n_in,
                              void* d_out, int out_size, void* d_ws, size_t ws_size,
                              hipStream_t stream){
  const float* cur  = (const float*)d_in[0];
  const float* ctx  = (const float*)d_in[1];
  const float* cand = (const float*)d_in[2];
  const float* Wq   = (const float*)d_in[3];
  const float* Wk   = (const float*)d_in[4];
  const int*   mask = (const int*)d_in[5];
  int N = in_sizes[5];
  float* out = (float*)d_out;

  char* ws = (char*)d_ws;
  float* v      = (float*)ws;             // 512 B
  float* scores = (float*)(ws + 512);     // N*4, 16B-aligned

  int ktop = N / 2; if (ktop < 1) ktop = 1; if (ktop > 50) ktop = 50;
  int g_score = (N + 63) / 64;            // one 64-row tile per block

  k_prep<<<1, 256, 0, stream>>>(cur, ctx, Wq, Wk, v);
  k_score<<<g_score, 256, 0, stream>>>(cand, mask, v, scores, out, N);
  k_finish<<<1, 1024, 0, stream>>>(scores, out, N, ktop);
}

// Round 2
// 227.916 us; speedup vs baseline: 1.1473x; 1.1473x over previous
//
#include <hip/hip_runtime.h>
#include <math.h>

// AttentionDecoder R9: 6 kernels, parallel atomic-light tail.
// prep (wave-parallel MLP, zeroes hist) | score (PURE GEMV, proven) |
// hist (49 blocks, LDS hist, flush chains <=49/address, Z partials no atomics) |
// mid (1 blk: Z reduce + suffix scan -> u_lo) |
// gather (49 blocks -> per-block regions, ZERO global atomics) |
// fin (1 blk on C~few-hundred entries: select + renorm + categorical).
// R8 lesson: single-CU tail streaming 1.6MB + 200k expf visits = 88us
// (OccupancyPercent 0.17). Parallelize streaming; only O(C) work on one CU.
// R6 lesson: same-address global atomic ~50ns serialized; keep chains <=~100.

#define CAP 4096
#define SLOT 2048
#define MAXB 128
#define NEG_INF (-__builtin_inff())

// order-preserving float->uint mapping (monotone increasing)
__device__ __forceinline__ unsigned int f2ord(float f){
  unsigned int b = __float_as_uint(f);
  return (b & 0x80000000u) ? ~b : (b | 0x80000000u);
}
__device__ __forceinline__ unsigned int rotl32(unsigned int x, int d){
  return (x << d) | (x >> (32 - d));
}

// JAX partitionable threefry, key (0,42): x0=idx>>32(=0), x1=idx; bits=w0^w1.
// gumbel = -log(-log(u)), u = bitcast((bits>>9)|0x3f800000)-1 clamped to tiny.
__device__ float gumbel_from_idx(unsigned int idx){
  unsigned int x0 = 0u, x1 = idx;
  const unsigned int ks0 = 0u, ks1 = 42u;
  const unsigned int ks2 = 0u ^ 42u ^ 0x1BD11BDAu;
  x0 += ks0; x1 += ks1;
#define TF_RND(r) { x0 += x1; x1 = rotl32(x1, (r)); x1 ^= x0; }
  TF_RND(13) TF_RND(15) TF_RND(26) TF_RND(6)
  x0 += ks1; x1 += ks2 + 1u;
  TF_RND(17) TF_RND(29) TF_RND(16) TF_RND(24)
  x0 += ks2; x1 += ks0 + 2u;
  TF_RND(13) TF_RND(15) TF_RND(26) TF_RND(6)
  x0 += ks0; x1 += ks1 + 3u;
  TF_RND(17) TF_RND(29) TF_RND(16) TF_RND(24)
  x0 += ks1; x1 += ks2 + 4u;
  TF_RND(13) TF_RND(15) TF_RND(26) TF_RND(6)
  x0 += ks2; x1 += ks0 + 5u;
#undef TF_RND
  unsigned int bits = x0 ^ x1;
  unsigned int fb = (bits >> 9) | 0x3f800000u;
  float f = __uint_as_float(fb) - 1.0f;
  float u = (f < 1.17549435e-38f) ? 1.17549435e-38f : f;
  return -logf(-logf(u));
}

// Wave-parallel MLP: q = Wq @ [cur;ctx] (half-wave per row, coalesced float4,
// 5-shfl reduce), then v = Wk^T q (split-K across 2 thread-halves).
// Also zeroes the global histogram for this iteration.
__global__ __launch_bounds__(256) void k_prep(const float* __restrict__ cur,
    const float* __restrict__ ctx, const float* __restrict__ Wq,
    const float* __restrict__ Wk, float* __restrict__ v,
    unsigned int* __restrict__ hist){
  __shared__ float q[128];
  __shared__ float vpart[256];
  int t = threadIdx.x;
  int lane = t & 63, wave = t >> 6;
  int hl = lane & 31, hi = lane >> 5;
  for (int k = t; k < 2048; k += 256) hist[k] = 0u;
  float4 cb0 = ((const float4*)cur)[hl];
  float4 cb1 = ((const float4*)ctx)[hl];
  const float4* Wq4 = (const float4*)Wq;
  #pragma unroll 4
  for (int i = 0; i < 16; ++i){
    int row = wave * 32 + 2 * i + hi;          // 4 waves x 16 iters x 2 rows = 128
    float4 w0 = Wq4[row * 64 + hl];            // coalesced 512B per half-wave
    float4 w1 = Wq4[row * 64 + 32 + hl];
    float d = fmaf(w0.x, cb0.x, fmaf(w0.y, cb0.y, fmaf(w0.z, cb0.z, w0.w * cb0.w)));
    d = fmaf(w1.x, cb1.x, fmaf(w1.y, cb1.y, fmaf(w1.z, cb1.z, fmaf(w1.w, cb1.w, d))));
    d += __shfl_xor(d, 1, 64);
    d += __shfl_xor(d, 2, 64);
    d += __shfl_xor(d, 4, 64);
    d += __shfl_xor(d, 8, 64);
    d += __shfl_xor(d, 16, 64);
    if (hl == 0) q[row] = d;
  }
  __syncthreads();
  // v[col] = sum_h q[h]*Wk[h*128+col]; split h-range across two 128-thread halves
  int col = t & 127, half = t >> 7;
  const float* wkp = Wk + half * 64 * 128 + col;
  const float* qp  = q + half * 64;
  float acc = 0.f;
  #pragma unroll 8
  for (int h = 0; h < 64; ++h) acc = fmaf(qp[h], wkp[h * 128], acc);
  vpart[t] = acc;
  __syncthreads();
  if (t < 128) v[t] = vpart[t] + vpart[t + 128];
}

// PURE GEMV (unchanged, proven). Half-wave per row (32 lanes x float4 = 512B),
// 16 rows/wave, 64 rows/block. All 8 loads issued before any FMA. No atomics.
__global__ __launch_bounds__(256) void k_score(const float* __restrict__ cand,
    const int* __restrict__ mask, const float* __restrict__ v,
    float* __restrict__ scores, float* __restrict__ out, int N){
  const float NLOG = logf(1e-10f);
  int t = threadIdx.x;
  int lane = t & 63, wave = t >> 6;
  int hi = lane >> 5, hl = lane & 31;
  float4 v4 = ((const float4*)v)[hl];
  const float4* cp = (const float4*)cand;
  int base = (blockIdx.x * 4 + wave) * 16;
  float4 c[8];
  #pragma unroll
  for (int k = 0; k < 8; ++k){                 // phase 1: 8 loads in flight
    int r = base + 2 * k + hi;
    r = (r < N) ? r : (N - 1);                 // clamp: load stays unconditional
    c[k] = cp[(size_t)r * 32 + hl];
  }
  float p[8];
  #pragma unroll
  for (int k = 0; k < 8; ++k)                  // phase 2: consume
    p[k] = fmaf(c[k].x, v4.x, fmaf(c[k].y, v4.y, fmaf(c[k].z, v4.z, c[k].w * v4.w)));
  #pragma unroll
  for (int k = 0; k < 8; ++k){                 // 8 independent 5-shfl chains
    p[k] += __shfl_xor(p[k], 1, 64);
    p[k] += __shfl_xor(p[k], 2, 64);
    p[k] += __shfl_xor(p[k], 4, 64);
    p[k] += __shfl_xor(p[k], 8, 64);
    p[k] += __shfl_xor(p[k], 16, 64);
  }
  float sv = p[0];
  #pragma unroll
  for (int k = 1; k < 8; ++k) sv = (hl == k) ? p[k] : sv;
  if (hl < 8){                                 // writer lanes
    int r = base + 2 * hl + hi;
    if (r < N) scores[r] = mask[r] ? sv : NEG_INF;
  }
  if (t < 16){                                 // default output value, float4
    int o4 = blockIdx.x * 16 + t;
    if (o4 * 4 + 3 < N){
      ((float4*)out)[o4] = make_float4(NLOG, NLOG, NLOG, NLOG);
    } else {
      #pragma unroll
      for (int e = 0; e < 4; ++e){ int i = o4 * 4 + e; if (i < N) out[i] = NLOG; }
    }
  }
}

// 49 blocks x 256 thr x 16 elems: LDS hist + block Z partial (no atomic).
// Flush: <= NB atomics per hist address (~2.5us worst serialized).
__global__ __launch_bounds__(256) void k_hist(const float* __restrict__ scores,
    unsigned int* __restrict__ hist, float* __restrict__ zpart, int N){
  __shared__ unsigned int lh[2048];
  __shared__ float wsum[4];
  int t = threadIdx.x;
  int lane = t & 63, wave = t >> 6;
  for (int k = t; k < 2048; k += 256) lh[k] = 0u;
  __syncthreads();
  float ez = 0.f;
  const float4* sp4 = (const float4*)scores;
  int nf = N >> 2;
  const float4 SENT = make_float4(NEG_INF, NEG_INF, NEG_INF, NEG_INF);
  int base = blockIdx.x * 1024;                // float4 units
  float4 c[4];
  #pragma unroll
  for (int k = 0; k < 4; ++k){
    int f = base + k * 256 + t;
    c[k] = (f < nf) ? sp4[f] : SENT;
  }
#define HVISIT(s_) { float sx = (s_); if (sx > NEG_INF){ \
    atomicAdd(&lh[f2ord(sx) >> 21], 1u); ez += expf(sx); } }
  #pragma unroll
  for (int k = 0; k < 4; ++k){
    HVISIT(c[k].x) HVISIT(c[k].y) HVISIT(c[k].z) HVISIT(c[k].w)
  }
  if (blockIdx.x == 0)
    for (int i = (nf << 2) + t; i < N; i += 256) HVISIT(scores[i])
#undef HVISIT
  #pragma unroll
  for (int off = 32; off; off >>= 1) ez += __shfl_xor(ez, off, 64);
  if (lane == 0) wsum[wave] = ez;
  __syncthreads();
  if (t == 0) zpart[blockIdx.x] = wsum[0] + wsum[1] + wsum[2] + wsum[3];
  for (int k = t; k < 2048; k += 256){
    unsigned int cc = lh[k];
    if (cc) atomicAdd(&hist[k], cc);
  }
}

// 1 block: Z = sum(zpart) -> scal_f[3]; hist suffix scan -> u_lo -> scal_u[1].
__global__ __launch_bounds__(256) void k_mid(const unsigned int* __restrict__ hist,
    const float* __restrict__ zpart, unsigned int* __restrict__ scal_u,
    int nb, int ktop){
  __shared__ unsigned int suf[256];
  __shared__ int csel_sh;
  int t = threadIdx.x;
  float z = 0.f;
  for (int j = t; j < nb; j += 256) z += zpart[j];
  if (t < 64){
    #pragma unroll
    for (int off = 32; off; off >>= 1) z += __shfl_xor(z, off, 64);
    if (t == 0) ((float*)scal_u)[3] = z;
  }
  unsigned int csum = 0;
  #pragma unroll
  for (int k = 0; k < 8; ++k) csum += hist[t * 8 + k];
  suf[t] = csum;
  if (t == 0) csel_sh = -1;
  __syncthreads();
  for (int d = 1; d < 256; d <<= 1){
    unsigned int add = (t + d < 256) ? suf[t + d] : 0u;
    __syncthreads();
    suf[t] += add;
    __syncthreads();
  }
  unsigned int st = suf[t];
  unsigned int sn = (t < 255) ? suf[t + 1] : 0u;
  if (st >= (unsigned)ktop && sn < (unsigned)ktop) csel_sh = t;   // unique
  __syncthreads();
  if (t == 0){
    int b_sel = 0;
    if (csel_sh >= 0){
      int c = csel_sh;
      unsigned int cum = (c < 255) ? suf[c + 1] : 0u;
      for (int b = 8 * c + 7; b >= 8 * c; --b){
        cum += hist[b];
        if (cum >= (unsigned)ktop){ b_sel = b; break; }
      }
    }
    scal_u[1] = ((unsigned int)b_sel) << 21;
  }
}

// 49 blocks: candidates >= u_lo into per-block region (LDS counter only).
__global__ __launch_bounds__(256) void k_gather(const float* __restrict__ scores,
    const unsigned int* __restrict__ scal_u, unsigned int* __restrict__ cnt,
    unsigned int* __restrict__ buf_idx, float* __restrict__ buf_s, int N){
  __shared__ int pos_sh;
  int t = threadIdx.x;
  if (t == 0) pos_sh = 0;
  __syncthreads();
  unsigned int u_lo = scal_u[1];
  const float4* sp4 = (const float4*)scores;
  int nf = N >> 2;
  const float4 SENT = make_float4(NEG_INF, NEG_INF, NEG_INF, NEG_INF);
  int base = blockIdx.x * 1024;                // float4 units
  size_t rbase = (size_t)blockIdx.x * SLOT;
  float4 c[4];
  #pragma unroll
  for (int k = 0; k < 4; ++k){
    int f = base + k * 256 + t;
    c[k] = (f < nf) ? sp4[f] : SENT;
  }
#define GVISIT(s_, i_) { float sx = (s_); if (sx > NEG_INF && f2ord(sx) >= u_lo){ \
    int p = atomicAdd(&pos_sh, 1); \
    if (p < SLOT){ buf_s[rbase + p] = sx; buf_idx[rbase + p] = (unsigned int)(i_); } } }
  #pragma unroll
  for (int k = 0; k < 4; ++k){
    int f = base + k * 256 + t;
    GVISIT(c[k].x, 4*f) GVISIT(c[k].y, 4*f+1) GVISIT(c[k].z, 4*f+2) GVISIT(c[k].w, 4*f+3)
  }
  if (blockIdx.x == 0)
    for (int i = (nf << 2) + t; i < N; i += 256) GVISIT(scores[i], i)
#undef GVISIT
  __syncthreads();
  if (t == 0) cnt[blockIdx.x] = (unsigned int)((pos_sh > SLOT) ? SLOT : pos_sh);
}

// 1 block, 1024 thr, only O(C) work: collect regions, exact rank-select,
// renorm + scatter-rewrite, threefry-gumbel categorical.
__global__ __launch_bounds__(1024) void k_fin(const unsigned int* __restrict__ cnt,
    const unsigned int* __restrict__ buf_idx, const float* __restrict__ buf_s,
    const unsigned int* __restrict__ scal_u, float* __restrict__ out,
    int N, int ktop, int nb){
  __shared__ float s_lds[CAP];
  __shared__ unsigned int i_lds[CAP];
  __shared__ unsigned int cnt_l[MAXB], offs[MAXB];
  __shared__ float wred[16];
  __shared__ float rv[16], rl[16];
  __shared__ unsigned int ri[16];
  __shared__ float thr_sh, lnD_sh;
  __shared__ int C_sh;
  int t = threadIdx.x;
  int lane = t & 63, wave = t >> 6;
  if (t < nb) cnt_l[t] = cnt[t];
  if (t == 0) thr_sh = NEG_INF;
  __syncthreads();
  if (t == 0){
    unsigned int acc = 0;
    for (int b = 0; b < nb; ++b){ offs[b] = acc; acc += cnt_l[b]; }
    C_sh = (acc > CAP) ? CAP : (int)acc;
  }
  __syncthreads();
  for (int b = 0; b < nb; ++b){
    unsigned int cb = cnt_l[b], ob = offs[b];
    size_t rbase = (size_t)b * SLOT;
    for (unsigned int j = t; j < cb; j += 1024){
      unsigned int p = ob + j;
      if (p < CAP){ s_lds[p] = buf_s[rbase + j]; i_lds[p] = buf_idx[rbase + j]; }
    }
  }
  __syncthreads();
  int C = C_sh;
  // ---- exact rank-select on C entries (broadcast LDS reads) ----
  if (C > ktop){
    for (int j = t; j < C; j += 1024){
      float sj = s_lds[j];
      int g = 0, e = 0;
      for (int k2 = 0; k2 < C; ++k2){
        float sk = s_lds[k2];
        g += (sk > sj);
        e += (sk == sj);
      }
      if (g < ktop && g + e >= ktop) thr_sh = sj;   // all writers same value
    }
  }
  __syncthreads();
  float s_thr = thr_sh;
  float Z = ((const float*)scal_u)[3];
  float part = 0.f;
  for (int j = t; j < C; j += 1024){
    float sj = s_lds[j];
    if (sj >= s_thr) part += expf(sj);
  }
  #pragma unroll
  for (int off = 32; off; off >>= 1) part += __shfl_xor(part, off, 64);
  if (lane == 0) wred[wave] = part;
  __syncthreads();
  if (t == 0){
    float T = 0.f;
    for (int w = 0; w < 16; ++w) T += wred[w];
    lnD_sh = logf(T + 1e-10f * Z);       // D = Z*(sum_top p + 1e-10)
  }
  __syncthreads();
  float lnD = lnD_sh;
  // rewrite included entries (everything else already NLOG from k_score)
  for (int j = t; j < C; j += 1024){
    float sj = s_lds[j];
    if (sj >= s_thr) out[i_lds[j]] = logf(expf(sj - lnD) + 1e-10f);
  }
  // gumbel categorical over included entries, tie-break lower idx
  float bestv = NEG_INF, bestlogit = NEG_INF;
  unsigned int bestidx = 0xFFFFFFFFu;
  for (int j = t; j < C; j += 1024){
    float sj = s_lds[j];
    if (sj >= s_thr){
      unsigned int idx = i_lds[j];
      float logit = sj - lnD;            // log(filtered)
      float val = logit + gumbel_from_idx(idx);
      if (val > bestv || (val == bestv && idx < bestidx)){
        bestv = val; bestlogit = logit; bestidx = idx;
      }
    }
  }
  #pragma unroll
  for (int off = 32; off; off >>= 1){
    float ov = __shfl_xor(bestv, off, 64);
    float ol = __shfl_xor(bestlogit, off, 64);
    unsigned int oi = (unsigned int)__shfl_xor((int)bestidx, off, 64);
    if (ov > bestv || (ov == bestv && oi < bestidx)){
      bestv = ov; bestlogit = ol; bestidx = oi;
    }
  }
  if (lane == 0){ rv[wave] = bestv; rl[wave] = bestlogit; ri[wave] = bestidx; }
  __syncthreads();
  if (t == 0){
    for (int w = 1; w < 16; ++w){
      if (rv[w] > rv[0] || (rv[w] == rv[0] && ri[w] < ri[0])){
        rv[0] = rv[w]; rl[0] = rl[w]; ri[0] = ri[w];
      }
    }
    out[N] = rl[0];                 // log_prob_action
    out[N + 1] = (float)ri[0];      // action_idx
  }
}

extern "C" void kernel_launch(void* const* d_in, const int* in_sizes, int n_in,
                              void* d_out, int out_size, void* d_ws, size_t ws_size,
                              hipStream_t stream){
  const float* cur  = (const float*)d_in[0];
  const float* ctx  = (const float*)d_in[1];
  const float* cand = (const float*)d_in[2];
  const float* Wq   = (const float*)d_in[3];
  const float* Wk   = (const float*)d_in[4];
  const int*   mask = (const int*)d_in[5];
  int N = in_sizes[5];
  float* out = (float*)d_out;

  int nb = (N + 4095) / 4096;           // 49 for N=200000
  if (nb > MAXB) nb = MAXB;             // (N fixed at 200000; guard only)

  char* ws = (char*)d_ws;
  unsigned int* scal_u  = (unsigned int*)ws;                       // 256 B
  unsigned int* hist    = (unsigned int*)(ws + 256);               // 8192 B
  float*        v       = (float*)(ws + 256 + 8192);               // 512 B
  float*        zpart   = (float*)(ws + 256 + 8192 + 512);         // MAXB*4 B
  unsigned int* cnt     = (unsigned int*)(ws + 256 + 8192 + 512 + 512); // MAXB*4 B
  float*        scores  = (float*)(ws + 10240);                    // N*4, 16B-aligned
  char*         bufbase = ws + 10240 + ((size_t)N * 4 + 255 & ~255ull);
  float*        buf_s   = (float*)bufbase;                         // MAXB*SLOT*4
  unsigned int* buf_idx = (unsigned int*)(bufbase + (size_t)MAXB * SLOT * 4);

  int ktop = N / 2; if (ktop < 1) ktop = 1; if (ktop > 50) ktop = 50;
  int g_score = (N + 63) / 64;          // one 64-row tile per block

  k_prep<<<1, 256, 0, stream>>>(cur, ctx, Wq, Wk, v, hist);
  k_score<<<g_score, 256, 0, stream>>>(cand, mask, v, scores, out, N);
  k_hist<<<nb, 256, 0, stream>>>(scores, hist, zpart, N);
  k_mid<<<1, 256, 0, stream>>>(hist, zpart, scal_u, nb, ktop);
  k_gather<<<nb, 256, 0, stream>>>(scores, scal_u, cnt, buf_idx, buf_s, N);
  k_fin<<<1, 1024, 0, stream>>>(cnt, buf_idx, buf_s, scal_u, out, N, ktop, nb);
}